// Round 1
// baseline (20974.173 us; speedup 1.0000x reference)
//
#include <hip/hip_runtime.h>
#include <cstdint>
#include <cstddef>

#define LSEQ 512
#define NBLK 192
#define ASZ (128*256*8)   // halfs per h parity plane (512 KB)

typedef _Float16 f16;
typedef f16 f16x8 __attribute__((ext_vector_type(8)));
typedef float f32x4 __attribute__((ext_vector_type(4)));
typedef int v4i __attribute__((ext_vector_type(4)));
typedef unsigned long long u64t;

#define MFMA16(a, b, c) __builtin_amdgcn_mfma_f32_16x16x32_f16(a, b, c, 0, 0, 0)

static __device__ __forceinline__ float sigm(float x){ return 1.f/(1.f+__expf(-x)); }
static __device__ __forceinline__ float tanh_f(float x){
    x = fminf(fmaxf(x,-15.f),15.f);
    float t = __expf(-2.f*x);
    return (1.f-t)/(1.f+t);
}
static __device__ __forceinline__ f16x8 cvt8(const float* s){
    float4 a = *(const float4*)s, b = *(const float4*)(s+4);
    f16x8 v = {(f16)a.x,(f16)a.y,(f16)a.z,(f16)a.w,(f16)b.x,(f16)b.y,(f16)b.z,(f16)b.w};
    return v;
}

// ---- Cached 16B load (aux=0: L1+L2 cached). Coherence is provided by the
// per-step agent-acquire fence (buffer_inv) at grid_barrier exit: every h
// line is fetched from the IC (device coherence point) at most once per XCD
// per step and then broadcast from L2 — vs the old SC0|SC1 bypass where ALL
// 96 MB/step of A-panel reads were IC-served (the measured latency wall).
static __device__ __forceinline__ uint4 cc_load(const char* base, int voff){
    __amdgpu_buffer_rsrc_t srd =
        __builtin_amdgcn_make_buffer_rsrc((void*)base, (short)0, -1, 0x00020000);
    v4i r = __builtin_amdgcn_raw_buffer_load_b128(srd, voff, 0, 0);
    return __builtin_bit_cast(uint4, r);
}
// 8B IC-coherent atomic ops (h stores + final read + barrier) — R7-proven.
static __device__ __forceinline__ u64t hload(const u64t* p){
    return __hip_atomic_load(p, __ATOMIC_RELAXED, __HIP_MEMORY_SCOPE_AGENT);
}
static __device__ __forceinline__ void hstore(u64t* p, u64t v){
    __hip_atomic_store(p, v, __ATOMIC_RELAXED, __HIP_MEMORY_SCOPE_AGENT);
}
union U64F16 { u64t q; f16 h[4]; };
union U2F16x8 { u64t q[2]; f16x8 v; };

// Raw chunk barriers: keep vmcnt (prefetches) alive across s_barrier.
#define SYNC_RAW()  __builtin_amdgcn_s_barrier()
#define SYNC_LGKM() do { __builtin_amdgcn_s_waitcnt(0xC07F); __builtin_amdgcn_s_barrier(); } while(0)

// Grid barrier: drain own vmem (stores acked at IC), one relaxed IC add,
// relaxed spin. On exit: agent-acquire fence -> buffer_inv (L1+L2
// invalidate) so this step's h reads can use normal caching and be served
// from the XCD-local L2 after first touch. vmcnt is already 0 here so the
// fence's waitcnt is free; nothing reusable lives in L2 across steps
// (weights are VGPR-resident).
static __device__ __forceinline__ void grid_barrier(int* bar){
    __builtin_amdgcn_s_waitcnt(0x0f70);   // vmcnt(0)
    __syncthreads();
    if (threadIdx.x == 0){
        int g = __hip_atomic_load(&bar[32], __ATOMIC_RELAXED, __HIP_MEMORY_SCOPE_AGENT);
        int old = __hip_atomic_fetch_add(&bar[0], 1, __ATOMIC_RELAXED, __HIP_MEMORY_SCOPE_AGENT);
        if (old == NBLK - 1){
            __hip_atomic_store(&bar[0], 0, __ATOMIC_RELAXED, __HIP_MEMORY_SCOPE_AGENT);
            __hip_atomic_store(&bar[32], g + 1, __ATOMIC_RELAXED, __HIP_MEMORY_SCOPE_AGENT);
        } else {
            while (__hip_atomic_load(&bar[32], __ATOMIC_RELAXED, __HIP_MEMORY_SCOPE_AGENT) == g)
                __builtin_amdgcn_s_sleep(2);
        }
    }
    __syncthreads();
    __builtin_amdgcn_fence(__ATOMIC_ACQUIRE, "agent");
}

// Blocks 0..127: L1 (mh=blk>>6 m-half 128 rows, nb=blk&63 -> 16 j-cols x 4 gates).
// Blocks 128..191: L0 (all 256 rows, nb -> 16 j-cols x 4 gates).
// Waves: nh=wav&1 (col-half, 32 gate-cols), kh=wav>>1 (K-half).
// Weights VGPR-resident fp16 frags; h planes [kc8 128][m 256][8] fp16,
// written via IC atomics, read via L2-cached loads (per-step inv).
__global__ void __launch_bounds__(256, 1) lstm_persist(
    const float* __restrict__ seq,
    const float* __restrict__ Wih0, const float* __restrict__ Whh0,
    const float* __restrict__ bih0, const float* __restrict__ bhh0,
    const float* __restrict__ Wih1, const float* __restrict__ Whh1,
    const float* __restrict__ bih1, const float* __restrict__ bhh1,
    const float* __restrict__ linW, const float* __restrict__ linb,
    f16* __restrict__ A0, f16* __restrict__ A1, float* __restrict__ out,
    int* __restrict__ bar)
{
    __shared__ char  pool[34816] __attribute__((aligned(16)));
    __shared__ float ldsX[1536];
    __shared__ float ldsWx[384];
    __shared__ float ldsBias[64];
    float* poolf = (float*)pool;

    const int tid = threadIdx.x, lane = tid & 63, wav = tid >> 6;
    const int quad = lane >> 4, l15 = lane & 15;
    const int nh = wav & 1, kh = wav >> 1;
    const int blk = blockIdx.x;

    if (blk < 128){
        // ======================= L1 =======================
        const int mh = blk >> 6, nb = blk & 63;
        const int m0 = mh * 128, j0 = nb * 16;
        if (tid < 64){
            int R = (tid >> 4) * 1024 + j0 + (tid & 15);
            ldsBias[tid] = bih1[R] + bhh1[R];
        }
        // weights: w1[kg][nt], k = kh*1024 + kg*32 + quad*8 (kh=0 -> Wih1, kh=1 -> Whh1)
        f16x8 w1[32][2];
        {
            const float* Wsrc = kh ? Whh1 : Wih1;
            #pragma unroll
            for (int nt = 0; nt < 2; ++nt){
                int ct = nh * 32 + nt * 16 + l15;
                size_t Roff = (size_t)((ct >> 4) * 1024 + j0 + (ct & 15)) * 1024;
                #pragma unroll
                for (int kg = 0; kg < 32; ++kg)
                    w1[kg][nt] = cvt8(Wsrc + Roff + kg * 32 + quad * 8);
            }
        }
        float c1[8] = {0,0,0,0,0,0,0,0};

        for (int p = 0; p <= LSEQ; ++p){
            if (p >= 1){
                const char* P0 = (const char*)(A0 + (size_t)((p + 1) & 1) * ASZ); // h0[p-1]
                const char* P1 = (const char*)(A1 + (size_t)(p & 1) * ASZ);       // h1[p-2]
                u64t* W1p = (u64t*)(A1 + (size_t)((p + 1) & 1) * ASZ);            // h1[p-1]

                f32x4 acc[8][2];
                #pragma unroll
                for (int a = 0; a < 8; ++a){ acc[a][0] = (f32x4){0,0,0,0}; acc[a][1] = (f32x4){0,0,0,0}; }

                uint4 st[2][4];
                #pragma unroll
                for (int i = 0; i < 4; ++i){
                    int idx = i * 256 + tid, kc8l = idx >> 7, ml = idx & 127;
                    st[0][i] = cc_load(P0, ((kc8l) * 256 + m0 + ml) * 16);
                    st[1][i] = cc_load(P0, ((8 + kc8l) * 256 + m0 + ml) * 16);
                }
                #pragma unroll
                for (int c = 0; c < 32; ++c){
                    SYNC_RAW();                               // buf[c&1] readers (iter c-2) done
                    {
                        char* dst = pool + (c & 1) * 16512;
                        #pragma unroll
                        for (int i = 0; i < 4; ++i){
                            int idx = i * 256 + tid, kc8l = idx >> 7, ml = idx & 127;
                            *(uint4*)(dst + kc8l * 2064 + ml * 16) = st[c & 1][i];
                        }
                    }
                    SYNC_LGKM();                              // writes visible
                    if (c < 30){
                        const int n = c + 2;
                        const char* P = (n < 16) ? P0 : P1;
                        const int kb = (n < 16) ? n * 8 : (n - 16) * 8;
                        #pragma unroll
                        for (int i = 0; i < 4; ++i){
                            int idx = i * 256 + tid, kc8l = idx >> 7, ml = idx & 127;
                            st[c & 1][i] = cc_load(P, ((kb + kc8l) * 256 + m0 + ml) * 16);
                        }
                    }
                    if (kh == ((c < 16) ? 0 : 1)){
                        const char* la = pool + (c & 1) * 16512;
                        const int cl = (c < 16) ? c : c - 16;
                        #pragma unroll
                        for (int kgl = 0; kgl < 2; ++kgl){
                            const int ckg = cl * 2 + kgl;
                            #pragma unroll
                            for (int mt = 0; mt < 8; ++mt){
                                f16x8 af = *(const f16x8*)(la + (kgl * 4 + quad) * 2064 + (mt * 16 + l15) * 16);
                                acc[mt][0] = MFMA16(af, w1[ckg][0], acc[mt][0]);
                                acc[mt][1] = MFMA16(af, w1[ckg][1], acc[mt][1]);
                            }
                        }
                    }
                }
                // ---- epilogue: K-reduce (kh1 -> kh0) via LDS, gather, pointwise ----
                __syncthreads();
                if (kh == 1){
                    #pragma unroll
                    for (int mt = 0; mt < 8; ++mt)
                        #pragma unroll
                        for (int nt = 0; nt < 2; ++nt){
                            int ct = nh * 32 + nt * 16 + l15;
                            *(f32x4*)(poolf + ct * 132 + mt * 16 + quad * 4) = acc[mt][nt];
                        }
                }
                __syncthreads();
                if (kh == 0){
                    #pragma unroll
                    for (int mt = 0; mt < 8; ++mt)
                        #pragma unroll
                        for (int nt = 0; nt < 2; ++nt){
                            int ct = nh * 32 + nt * 16 + l15;
                            f32x4 v = acc[mt][nt] + *(const f32x4*)(poolf + ct * 132 + mt * 16 + quad * 4);
                            *(f32x4*)(poolf + ct * 132 + mt * 16 + quad * 4) = v;
                        }
                }
                __syncthreads();
                {
                    const int m = tid >> 1, jh = tid & 1;
                    float hq[8];
                    #pragma unroll
                    for (int jj = 0; jj < 8; ++jj){
                        int j = jh * 8 + jj;
                        float gv[4];
                        #pragma unroll
                        for (int g = 0; g < 4; ++g)
                            gv[g] = poolf[(g * 16 + j) * 132 + m] + ldsBias[g * 16 + j];
                        float I = sigm(gv[0]), F = sigm(gv[1]), G = tanh_f(gv[2]), O = sigm(gv[3]);
                        float cn = F * c1[jj] + I * G;
                        c1[jj] = cn;
                        hq[jj] = O * tanh_f(cn);
                    }
                    const int kc8 = nb * 2 + jh;
                    #pragma unroll
                    for (int q = 0; q < 2; ++q){
                        U64F16 v;
                        #pragma unroll
                        for (int w = 0; w < 4; ++w) v.h[w] = (f16)hq[q * 4 + w];
                        hstore(W1p + (size_t)(kc8 * 256 + m0 + m) * 2 + q, v.q);
                    }
                }
            }
            grid_barrier(bar);
        }
    } else {
        // ======================= L0 =======================
        const int nb0 = blk - 128;
        const int j0 = nb0 * 16;
        if (tid < 64){
            int R = (tid >> 4) * 1024 + j0 + (tid & 15);
            ldsBias[tid] = bih0[R] + bhh0[R];
        }
        for (int t = tid; t < 384; t += 256){
            int ct = t / 6, i = t - ct * 6;
            int R = (ct >> 4) * 1024 + j0 + (ct & 15);
            ldsWx[t] = Wih0[(size_t)R * 6 + i];
        }
        f16x8 w0[16][2];
        {
            #pragma unroll
            for (int nt = 0; nt < 2; ++nt){
                int ct = nh * 32 + nt * 16 + l15;
                size_t Roff = (size_t)((ct >> 4) * 1024 + j0 + (ct & 15)) * 1024;
                #pragma unroll
                for (int kg = 0; kg < 16; ++kg)
                    w0[kg][nt] = cvt8(Whh0 + Roff + kh * 512 + kg * 32 + quad * 8);
            }
        }
        float c0[16];
        #pragma unroll
        for (int i = 0; i < 16; ++i) c0[i] = 0.f;

        for (int p = 0; p <= LSEQ; ++p){
            if (p < LSEQ){
                const char* P0 = (const char*)(A0 + (size_t)((p + 1) & 1) * ASZ); // h0[p-1]
                u64t* W0p = (u64t*)(A0 + (size_t)(p & 1) * ASZ);                  // h0[p]
                {   // stage x[p]
                    const float2* xp = (const float2*)(seq + (size_t)p * 1536);
                    float2* xd = (float2*)ldsX;
                    for (int i = tid; i < 768; i += 256) xd[i] = xp[i];
                }
                f32x4 acc[16][2];
                #pragma unroll
                for (int a = 0; a < 16; ++a){ acc[a][0] = (f32x4){0,0,0,0}; acc[a][1] = (f32x4){0,0,0,0}; }

                uint4 st[2][4];
                #pragma unroll
                for (int i = 0; i < 4; ++i){
                    int idx = i * 256 + tid, kc8l = idx >> 8, ml = idx & 255;
                    st[0][i] = cc_load(P0, ((kc8l) * 256 + ml) * 16);
                    st[1][i] = cc_load(P0, ((4 + kc8l) * 256 + ml) * 16);
                }
                #pragma unroll
                for (int c = 0; c < 32; ++c){
                    SYNC_RAW();
                    {
                        char* dst = pool + (c & 1) * 16448;
                        #pragma unroll
                        for (int i = 0; i < 4; ++i){
                            int idx = i * 256 + tid, kc8l = idx >> 8, ml = idx & 255;
                            *(uint4*)(dst + kc8l * 4112 + ml * 16) = st[c & 1][i];
                        }
                    }
                    SYNC_LGKM();
                    if (c < 30){
                        const int kb = (c + 2) * 4;
                        #pragma unroll
                        for (int i = 0; i < 4; ++i){
                            int idx = i * 256 + tid, kc8l = idx >> 8, ml = idx & 255;
                            st[c & 1][i] = cc_load(P0, ((kb + kc8l) * 256 + ml) * 16);
                        }
                    }
                    if (kh == (c >> 4)){
                        const char* la = pool + (c & 1) * 16448;
                        const int ckg = c & 15;
                        #pragma unroll
                        for (int mt = 0; mt < 16; ++mt){
                            f16x8 af = *(const f16x8*)(la + quad * 4112 + (mt * 16 + l15) * 16);
                            acc[mt][0] = MFMA16(af, w0[ckg][0], acc[mt][0]);
                            acc[mt][1] = MFMA16(af, w0[ckg][1], acc[mt][1]);
                        }
                    }
                }
                // ---- epilogue: two m-half rounds ----
                #pragma unroll
                for (int hh = 0; hh < 2; ++hh){
                    __syncthreads();
                    if (kh == 1){
                        #pragma unroll
                        for (int mt = 8 * hh; mt < 8 * hh + 8; ++mt)
                            #pragma unroll
                            for (int nt = 0; nt < 2; ++nt){
                                int ct = nh * 32 + nt * 16 + l15;
                                *(f32x4*)(poolf + ct * 132 + (mt - 8 * hh) * 16 + quad * 4) = acc[mt][nt];
                            }
                    }
                    __syncthreads();
                    if (kh == 0){
                        #pragma unroll
                        for (int mt = 8 * hh; mt < 8 * hh + 8; ++mt)
                            #pragma unroll
                            for (int nt = 0; nt < 2; ++nt){
                                int ct = nh * 32 + nt * 16 + l15;
                                f32x4 v = acc[mt][nt] + *(const f32x4*)(poolf + ct * 132 + (mt - 8 * hh) * 16 + quad * 4);
                                *(f32x4*)(poolf + ct * 132 + (mt - 8 * hh) * 16 + quad * 4) = v;
                            }
                    }
                    __syncthreads();
                    {
                        const int ml = tid >> 1, jh = tid & 1;
                        const int ma = 128 * hh + ml;
                        float xv[6];
                        #pragma unroll
                        for (int i = 0; i < 6; ++i) xv[i] = ldsX[ma * 6 + i];
                        float hq[8];
                        #pragma unroll
                        for (int jj = 0; jj < 8; ++jj){
                            int j = jh * 8 + jj;
                            float gv[4];
                            #pragma unroll
                            for (int g = 0; g < 4; ++g){
                                float v = poolf[(g * 16 + j) * 132 + ml] + ldsBias[g * 16 + j];
                                #pragma unroll
                                for (int i = 0; i < 6; ++i) v += xv[i] * ldsWx[(g * 16 + j) * 6 + i];
                                gv[g] = v;
                            }
                            float I = sigm(gv[0]), F = sigm(gv[1]), G = tanh_f(gv[2]), O = sigm(gv[3]);
                            float cn = F * c0[hh * 8 + jj] + I * G;
                            c0[hh * 8 + jj] = cn;
                            hq[jj] = O * tanh_f(cn);
                        }
                        const int kc8 = nb0 * 2 + jh;
                        #pragma unroll
                        for (int q = 0; q < 2; ++q){
                            U64F16 v;
                            #pragma unroll
                            for (int w = 0; w < 4; ++w) v.h[w] = (f16)hq[q * 4 + w];
                            hstore(W0p + (size_t)(kc8 * 256 + ma) * 2 + q, v.q);
                        }
                    }
                }
            }
            grid_barrier(bar);
        }
        // ---- final linear on h1[511] (plane parity 1) ----
        {
            const u64t* hp = (const u64t*)(A1 + (size_t)ASZ);
            int n = nb0 * 4 + wav;
            float s = 0.f;
            #pragma unroll
            for (int u = 0; u < 2; ++u){
                int kc = u * 64 + lane;
                U2F16x8 t;
                t.q[0] = hload(hp + (size_t)(kc * 256 + n) * 2);
                t.q[1] = hload(hp + (size_t)(kc * 256 + n) * 2 + 1);
                #pragma unroll
                for (int j = 0; j < 8; ++j) s += (float)t.v[j] * linW[kc * 8 + j];
            }
            #pragma unroll
            for (int m = 32; m >= 1; m >>= 1) s += __shfl_xor(s, m, 64);
            if (lane == 0) out[n] = s + linb[0];
        }
    }
}

extern "C" void kernel_launch(void* const* d_in, const int* in_sizes, int n_in,
                              void* d_out, int out_size, void* d_ws, size_t ws_size,
                              hipStream_t stream)
{
    (void)in_sizes; (void)n_in; (void)out_size; (void)ws_size;
    const float* seq  = (const float*)d_in[0];
    const float* Wih0 = (const float*)d_in[1];
    const float* Whh0 = (const float*)d_in[2];
    const float* bih0 = (const float*)d_in[3];
    const float* bhh0 = (const float*)d_in[4];
    const float* Wih1 = (const float*)d_in[5];
    const float* Whh1 = (const float*)d_in[6];
    const float* bih1 = (const float*)d_in[7];
    const float* bhh1 = (const float*)d_in[8];
    const float* linW = (const float*)d_in[9];
    const float* linb = (const float*)d_in[10];
    float* outp = (float*)d_out;

    char* ws = (char*)d_ws;
    f16* A0p = (f16*)ws;                      // h0: [2][128 kc8][256 m][8] = 1 MB
    f16* A1p = (f16*)(ws + (1 << 20));        // h1: 1 MB
    int* bar = (int*)(ws + (2 << 20));        // barrier state

    (void)hipMemsetAsync(ws, 0, 2 << 20, stream);   // zero h parity planes
    (void)hipMemsetAsync(bar, 0, 256, stream);      // zero barrier

    lstm_persist<<<dim3(NBLK), dim3(256), 0, stream>>>(
        seq, Wih0, Whh0, bih0, bhh0, Wih1, Whh1, bih1, bhh1, linW, linb,
        A0p, A1p, outp, bar);
}

// Round 2
// 19530.388 us; speedup vs baseline: 1.0739x; 1.0739x over previous
//
#include <hip/hip_runtime.h>
#include <cstdint>
#include <cstddef>

#define LSEQ 512
#define NBLK 192
#define ASZ (128*256*8)   // halfs per h parity plane (512 KB)

typedef _Float16 f16;
typedef f16 f16x8 __attribute__((ext_vector_type(8)));
typedef float f32x4 __attribute__((ext_vector_type(4)));
typedef int v4i __attribute__((ext_vector_type(4)));
typedef unsigned long long u64t;

#define MFMA16(a, b, c) __builtin_amdgcn_mfma_f32_16x16x32_f16(a, b, c, 0, 0, 0)

static __device__ __forceinline__ float sigm(float x){ return 1.f/(1.f+__expf(-x)); }
static __device__ __forceinline__ float tanh_f(float x){
    x = fminf(fmaxf(x,-15.f),15.f);
    float t = __expf(-2.f*x);
    return (1.f-t)/(1.f+t);
}
static __device__ __forceinline__ f16x8 cvt8(const float* s){
    float4 a = *(const float4*)s, b = *(const float4*)(s+4);
    f16x8 v = {(f16)a.x,(f16)a.y,(f16)a.z,(f16)a.w,(f16)b.x,(f16)b.y,(f16)b.z,(f16)b.w};
    return v;
}

// ---- IC-coherent 16B load (R0-proven): SC0|SC1 bypasses L1+L2, served at
// the Infinity Cache (device coherence point). Compiler-managed waitcnts.
// R1's cached+per-step-inv variant REGRESSED (staggered buffer_inv from 192
// blocks thrashes L2 all step) — do not reintroduce.
static __device__ __forceinline__ uint4 ic_load(const char* base, int voff){
    __amdgpu_buffer_rsrc_t srd =
        __builtin_amdgcn_make_buffer_rsrc((void*)base, (short)0, -1, 0x00020000);
    v4i r = __builtin_amdgcn_raw_buffer_load_b128(srd, voff, 0, 0x11);
    return __builtin_bit_cast(uint4, r);
}
// 8B IC-coherent atomic ops (h stores + final read + barrier) — R7-proven.
static __device__ __forceinline__ u64t hload(const u64t* p){
    return __hip_atomic_load(p, __ATOMIC_RELAXED, __HIP_MEMORY_SCOPE_AGENT);
}
static __device__ __forceinline__ void hstore(u64t* p, u64t v){
    __hip_atomic_store(p, v, __ATOMIC_RELAXED, __HIP_MEMORY_SCOPE_AGENT);
}
union U64F16 { u64t q; f16 h[4]; };
union U2F16x8 { u64t q[2]; f16x8 v; };

// Raw chunk barriers: keep vmcnt (prefetches) alive across s_barrier.
#define SYNC_RAW()  __builtin_amdgcn_s_barrier()
#define SYNC_LGKM() do { __builtin_amdgcn_s_waitcnt(0xC07F); __builtin_amdgcn_s_barrier(); } while(0)

// Two-level grid barrier: 192 same-address IC RMWs serialize; split into
// 8 group counters (distinct 64B lines, 24 arrivals each, parallel at the
// IC) + 8 root RMWs. Same epoch/reset invariants as the R0-proven single
// level barrier, applied twice. Drain own vmem first (h stores acked at
// IC); relaxed spin with s_sleep.
#define BAR_ROOT 128
#define BAR_REL  160
static __device__ __forceinline__ void grid_barrier(int* bar, int grp){
    __builtin_amdgcn_s_waitcnt(0x0f70);   // vmcnt(0)
    __syncthreads();
    if (threadIdx.x == 0){
        int g = __hip_atomic_load(&bar[BAR_REL], __ATOMIC_RELAXED, __HIP_MEMORY_SCOPE_AGENT);
        int old = __hip_atomic_fetch_add(&bar[grp * 16], 1, __ATOMIC_RELAXED, __HIP_MEMORY_SCOPE_AGENT);
        if (old == (NBLK / 8) - 1){
            // last of group: reset group counter (next epoch's arrivals can
            // only come after release), then arrive at root.
            __hip_atomic_store(&bar[grp * 16], 0, __ATOMIC_RELAXED, __HIP_MEMORY_SCOPE_AGENT);
            int r = __hip_atomic_fetch_add(&bar[BAR_ROOT], 1, __ATOMIC_RELAXED, __HIP_MEMORY_SCOPE_AGENT);
            if (r == 7){
                __hip_atomic_store(&bar[BAR_ROOT], 0, __ATOMIC_RELAXED, __HIP_MEMORY_SCOPE_AGENT);
                __hip_atomic_store(&bar[BAR_REL], g + 1, __ATOMIC_RELAXED, __HIP_MEMORY_SCOPE_AGENT);
            } else {
                while (__hip_atomic_load(&bar[BAR_REL], __ATOMIC_RELAXED, __HIP_MEMORY_SCOPE_AGENT) == g)
                    __builtin_amdgcn_s_sleep(1);
            }
        } else {
            while (__hip_atomic_load(&bar[BAR_REL], __ATOMIC_RELAXED, __HIP_MEMORY_SCOPE_AGENT) == g)
                __builtin_amdgcn_s_sleep(2);
        }
    }
    __syncthreads();
}

// Blocks 0..127: L1 (mh=blk>>6 m-half 128 rows, nb=blk&63 -> 16 j-cols x 4 gates).
// Blocks 128..191: L0 (all 256 rows, nb -> 16 j-cols x 4 gates).
// Waves: nh=wav&1 (col-half, 32 gate-cols), kh=wav>>1 (K-half).
// Weights VGPR-resident fp16 frags; h planes [kc8 128][m 256][8] fp16 via IC.
// Prefetch depth 4 chunks (R2): ~16x16B loads in flight per thread to cover
// loaded-IC latency; LDS stays double-buffered.
__global__ void __launch_bounds__(256, 1) lstm_persist(
    const float* __restrict__ seq,
    const float* __restrict__ Wih0, const float* __restrict__ Whh0,
    const float* __restrict__ bih0, const float* __restrict__ bhh0,
    const float* __restrict__ Wih1, const float* __restrict__ Whh1,
    const float* __restrict__ bih1, const float* __restrict__ bhh1,
    const float* __restrict__ linW, const float* __restrict__ linb,
    f16* __restrict__ A0, f16* __restrict__ A1, float* __restrict__ out,
    int* __restrict__ bar)
{
    __shared__ char  pool[34816] __attribute__((aligned(16)));
    __shared__ float ldsX[1536];
    __shared__ float ldsWx[384];
    __shared__ float ldsBias[64];
    float* poolf = (float*)pool;

    const int tid = threadIdx.x, lane = tid & 63, wav = tid >> 6;
    const int quad = lane >> 4, l15 = lane & 15;
    const int nh = wav & 1, kh = wav >> 1;
    const int blk = blockIdx.x;
    const int grp = blk & 7;

    if (blk < 128){
        // ======================= L1 =======================
        const int mh = blk >> 6, nb = blk & 63;
        const int m0 = mh * 128, j0 = nb * 16;
        if (tid < 64){
            int R = (tid >> 4) * 1024 + j0 + (tid & 15);
            ldsBias[tid] = bih1[R] + bhh1[R];
        }
        // weights: w1[kg][nt], k = kh*1024 + kg*32 + quad*8 (kh=0 -> Wih1, kh=1 -> Whh1)
        f16x8 w1[32][2];
        {
            const float* Wsrc = kh ? Whh1 : Wih1;
            #pragma unroll
            for (int nt = 0; nt < 2; ++nt){
                int ct = nh * 32 + nt * 16 + l15;
                size_t Roff = (size_t)((ct >> 4) * 1024 + j0 + (ct & 15)) * 1024;
                #pragma unroll
                for (int kg = 0; kg < 32; ++kg)
                    w1[kg][nt] = cvt8(Wsrc + Roff + kg * 32 + quad * 8);
            }
        }
        float c1[8] = {0,0,0,0,0,0,0,0};

        for (int p = 0; p <= LSEQ; ++p){
            if (p >= 1){
                const char* P0 = (const char*)(A0 + (size_t)((p + 1) & 1) * ASZ); // h0[p-1]
                const char* P1 = (const char*)(A1 + (size_t)(p & 1) * ASZ);       // h1[p-2]
                u64t* W1p = (u64t*)(A1 + (size_t)((p + 1) & 1) * ASZ);            // h1[p-1]

                f32x4 acc[8][2];
                #pragma unroll
                for (int a = 0; a < 8; ++a){ acc[a][0] = (f32x4){0,0,0,0}; acc[a][1] = (f32x4){0,0,0,0}; }

                uint4 st[4][4];
                #pragma unroll
                for (int n = 0; n < 4; ++n)
                    #pragma unroll
                    for (int i = 0; i < 4; ++i){
                        int idx = i * 256 + tid, kc8l = idx >> 7, ml = idx & 127;
                        st[n][i] = ic_load(P0, ((n * 8 + kc8l) * 256 + m0 + ml) * 16);
                    }
                #pragma unroll
                for (int c = 0; c < 32; ++c){
                    SYNC_RAW();                               // buf[c&1] readers (iter c-2) done
                    {
                        char* dst = pool + (c & 1) * 16512;
                        #pragma unroll
                        for (int i = 0; i < 4; ++i){
                            int idx = i * 256 + tid, kc8l = idx >> 7, ml = idx & 127;
                            *(uint4*)(dst + kc8l * 2064 + ml * 16) = st[c & 3][i];
                        }
                    }
                    SYNC_LGKM();                              // writes visible
                    if (c < 28){
                        const int n = c + 4;
                        const char* P = (n < 16) ? P0 : P1;
                        const int kb = (n < 16) ? n * 8 : (n - 16) * 8;
                        #pragma unroll
                        for (int i = 0; i < 4; ++i){
                            int idx = i * 256 + tid, kc8l = idx >> 7, ml = idx & 127;
                            st[c & 3][i] = ic_load(P, ((kb + kc8l) * 256 + m0 + ml) * 16);
                        }
                    }
                    if (kh == ((c < 16) ? 0 : 1)){
                        const char* la = pool + (c & 1) * 16512;
                        const int cl = (c < 16) ? c : c - 16;
                        #pragma unroll
                        for (int kgl = 0; kgl < 2; ++kgl){
                            const int ckg = cl * 2 + kgl;
                            #pragma unroll
                            for (int mt = 0; mt < 8; ++mt){
                                f16x8 af = *(const f16x8*)(la + (kgl * 4 + quad) * 2064 + (mt * 16 + l15) * 16);
                                acc[mt][0] = MFMA16(af, w1[ckg][0], acc[mt][0]);
                                acc[mt][1] = MFMA16(af, w1[ckg][1], acc[mt][1]);
                            }
                        }
                    }
                }
                // ---- epilogue: K-reduce (kh1 -> kh0) via LDS, gather, pointwise ----
                __syncthreads();
                if (kh == 1){
                    #pragma unroll
                    for (int mt = 0; mt < 8; ++mt)
                        #pragma unroll
                        for (int nt = 0; nt < 2; ++nt){
                            int ct = nh * 32 + nt * 16 + l15;
                            *(f32x4*)(poolf + ct * 132 + mt * 16 + quad * 4) = acc[mt][nt];
                        }
                }
                __syncthreads();
                if (kh == 0){
                    #pragma unroll
                    for (int mt = 0; mt < 8; ++mt)
                        #pragma unroll
                        for (int nt = 0; nt < 2; ++nt){
                            int ct = nh * 32 + nt * 16 + l15;
                            f32x4 v = acc[mt][nt] + *(const f32x4*)(poolf + ct * 132 + mt * 16 + quad * 4);
                            *(f32x4*)(poolf + ct * 132 + mt * 16 + quad * 4) = v;
                        }
                }
                __syncthreads();
                {
                    const int m = tid >> 1, jh = tid & 1;
                    float hq[8];
                    #pragma unroll
                    for (int jj = 0; jj < 8; ++jj){
                        int j = jh * 8 + jj;
                        float gv[4];
                        #pragma unroll
                        for (int g = 0; g < 4; ++g)
                            gv[g] = poolf[(g * 16 + j) * 132 + m] + ldsBias[g * 16 + j];
                        float I = sigm(gv[0]), F = sigm(gv[1]), G = tanh_f(gv[2]), O = sigm(gv[3]);
                        float cn = F * c1[jj] + I * G;
                        c1[jj] = cn;
                        hq[jj] = O * tanh_f(cn);
                    }
                    const int kc8 = nb * 2 + jh;
                    #pragma unroll
                    for (int q = 0; q < 2; ++q){
                        U64F16 v;
                        #pragma unroll
                        for (int w = 0; w < 4; ++w) v.h[w] = (f16)hq[q * 4 + w];
                        hstore(W1p + (size_t)(kc8 * 256 + m0 + m) * 2 + q, v.q);
                    }
                }
            }
            grid_barrier(bar, grp);
        }
    } else {
        // ======================= L0 =======================
        const int nb0 = blk - 128;
        const int j0 = nb0 * 16;
        if (tid < 64){
            int R = (tid >> 4) * 1024 + j0 + (tid & 15);
            ldsBias[tid] = bih0[R] + bhh0[R];
        }
        for (int t = tid; t < 384; t += 256){
            int ct = t / 6, i = t - ct * 6;
            int R = (ct >> 4) * 1024 + j0 + (ct & 15);
            ldsWx[t] = Wih0[(size_t)R * 6 + i];
        }
        f16x8 w0[16][2];
        {
            #pragma unroll
            for (int nt = 0; nt < 2; ++nt){
                int ct = nh * 32 + nt * 16 + l15;
                size_t Roff = (size_t)((ct >> 4) * 1024 + j0 + (ct & 15)) * 1024;
                #pragma unroll
                for (int kg = 0; kg < 16; ++kg)
                    w0[kg][nt] = cvt8(Whh0 + Roff + kh * 512 + kg * 32 + quad * 8);
            }
        }
        float c0[16];
        #pragma unroll
        for (int i = 0; i < 16; ++i) c0[i] = 0.f;

        for (int p = 0; p <= LSEQ; ++p){
            if (p < LSEQ){
                const char* P0 = (const char*)(A0 + (size_t)((p + 1) & 1) * ASZ); // h0[p-1]
                u64t* W0p = (u64t*)(A0 + (size_t)(p & 1) * ASZ);                  // h0[p]
                {   // stage x[p]
                    const float2* xp = (const float2*)(seq + (size_t)p * 1536);
                    float2* xd = (float2*)ldsX;
                    for (int i = tid; i < 768; i += 256) xd[i] = xp[i];
                }
                f32x4 acc[16][2];
                #pragma unroll
                for (int a = 0; a < 16; ++a){ acc[a][0] = (f32x4){0,0,0,0}; acc[a][1] = (f32x4){0,0,0,0}; }

                uint4 st[4][4];
                #pragma unroll
                for (int n = 0; n < 4; ++n)
                    #pragma unroll
                    for (int i = 0; i < 4; ++i){
                        int idx = i * 256 + tid, kc8l = idx >> 8, ml = idx & 255;
                        st[n][i] = ic_load(P0, ((n * 4 + kc8l) * 256 + ml) * 16);
                    }
                #pragma unroll
                for (int c = 0; c < 32; ++c){
                    SYNC_RAW();
                    {
                        char* dst = pool + (c & 1) * 16448;
                        #pragma unroll
                        for (int i = 0; i < 4; ++i){
                            int idx = i * 256 + tid, kc8l = idx >> 8, ml = idx & 255;
                            *(uint4*)(dst + kc8l * 4112 + ml * 16) = st[c & 3][i];
                        }
                    }
                    SYNC_LGKM();
                    if (c < 28){
                        const int kb = (c + 4) * 4;
                        #pragma unroll
                        for (int i = 0; i < 4; ++i){
                            int idx = i * 256 + tid, kc8l = idx >> 8, ml = idx & 255;
                            st[c & 3][i] = ic_load(P0, ((kb + kc8l) * 256 + ml) * 16);
                        }
                    }
                    if (kh == (c >> 4)){
                        const char* la = pool + (c & 1) * 16448;
                        const int ckg = c & 15;
                        #pragma unroll
                        for (int mt = 0; mt < 16; ++mt){
                            f16x8 af = *(const f16x8*)(la + quad * 4112 + (mt * 16 + l15) * 16);
                            acc[mt][0] = MFMA16(af, w0[ckg][0], acc[mt][0]);
                            acc[mt][1] = MFMA16(af, w0[ckg][1], acc[mt][1]);
                        }
                    }
                }
                // ---- epilogue: two m-half rounds ----
                #pragma unroll
                for (int hh = 0; hh < 2; ++hh){
                    __syncthreads();
                    if (kh == 1){
                        #pragma unroll
                        for (int mt = 8 * hh; mt < 8 * hh + 8; ++mt)
                            #pragma unroll
                            for (int nt = 0; nt < 2; ++nt){
                                int ct = nh * 32 + nt * 16 + l15;
                                *(f32x4*)(poolf + ct * 132 + (mt - 8 * hh) * 16 + quad * 4) = acc[mt][nt];
                            }
                    }
                    __syncthreads();
                    if (kh == 0){
                        #pragma unroll
                        for (int mt = 8 * hh; mt < 8 * hh + 8; ++mt)
                            #pragma unroll
                            for (int nt = 0; nt < 2; ++nt){
                                int ct = nh * 32 + nt * 16 + l15;
                                f32x4 v = acc[mt][nt] + *(const f32x4*)(poolf + ct * 132 + (mt - 8 * hh) * 16 + quad * 4);
                                *(f32x4*)(poolf + ct * 132 + (mt - 8 * hh) * 16 + quad * 4) = v;
                            }
                    }
                    __syncthreads();
                    {
                        const int ml = tid >> 1, jh = tid & 1;
                        const int ma = 128 * hh + ml;
                        float xv[6];
                        #pragma unroll
                        for (int i = 0; i < 6; ++i) xv[i] = ldsX[ma * 6 + i];
                        float hq[8];
                        #pragma unroll
                        for (int jj = 0; jj < 8; ++jj){
                            int j = jh * 8 + jj;
                            float gv[4];
                            #pragma unroll
                            for (int g = 0; g < 4; ++g){
                                float v = poolf[(g * 16 + j) * 132 + ml] + ldsBias[g * 16 + j];
                                #pragma unroll
                                for (int i = 0; i < 6; ++i) v += xv[i] * ldsWx[(g * 16 + j) * 6 + i];
                                gv[g] = v;
                            }
                            float I = sigm(gv[0]), F = sigm(gv[1]), G = tanh_f(gv[2]), O = sigm(gv[3]);
                            float cn = F * c0[hh * 8 + jj] + I * G;
                            c0[hh * 8 + jj] = cn;
                            hq[jj] = O * tanh_f(cn);
                        }
                        const int kc8 = nb0 * 2 + jh;
                        #pragma unroll
                        for (int q = 0; q < 2; ++q){
                            U64F16 v;
                            #pragma unroll
                            for (int w = 0; w < 4; ++w) v.h[w] = (f16)hq[q * 4 + w];
                            hstore(W0p + (size_t)(kc8 * 256 + ma) * 2 + q, v.q);
                        }
                    }
                }
            }
            grid_barrier(bar, grp);
        }
        // ---- final linear on h1[511] (plane parity 1) ----
        {
            const u64t* hp = (const u64t*)(A1 + (size_t)ASZ);
            int n = nb0 * 4 + wav;
            float s = 0.f;
            #pragma unroll
            for (int u = 0; u < 2; ++u){
                int kc = u * 64 + lane;
                U2F16x8 t;
                t.q[0] = hload(hp + (size_t)(kc * 256 + n) * 2);
                t.q[1] = hload(hp + (size_t)(kc * 256 + n) * 2 + 1);
                #pragma unroll
                for (int j = 0; j < 8; ++j) s += (float)t.v[j] * linW[kc * 8 + j];
            }
            #pragma unroll
            for (int m = 32; m >= 1; m >>= 1) s += __shfl_xor(s, m, 64);
            if (lane == 0) out[n] = s + linb[0];
        }
    }
}

extern "C" void kernel_launch(void* const* d_in, const int* in_sizes, int n_in,
                              void* d_out, int out_size, void* d_ws, size_t ws_size,
                              hipStream_t stream)
{
    (void)in_sizes; (void)n_in; (void)out_size; (void)ws_size;
    const float* seq  = (const float*)d_in[0];
    const float* Wih0 = (const float*)d_in[1];
    const float* Whh0 = (const float*)d_in[2];
    const float* bih0 = (const float*)d_in[3];
    const float* bhh0 = (const float*)d_in[4];
    const float* Wih1 = (const float*)d_in[5];
    const float* Whh1 = (const float*)d_in[6];
    const float* bih1 = (const float*)d_in[7];
    const float* bhh1 = (const float*)d_in[8];
    const float* linW = (const float*)d_in[9];
    const float* linb = (const float*)d_in[10];
    float* outp = (float*)d_out;

    char* ws = (char*)d_ws;
    f16* A0p = (f16*)ws;                      // h0: [2][128 kc8][256 m][8] = 1 MB
    f16* A1p = (f16*)(ws + (1 << 20));        // h1: 1 MB
    int* bar = (int*)(ws + (2 << 20));        // barrier state (2-level: 8 groups + root + release)

    (void)hipMemsetAsync(ws, 0, 2 << 20, stream);   // zero h parity planes
    (void)hipMemsetAsync(bar, 0, 1024, stream);     // zero barrier state

    lstm_persist<<<dim3(NBLK), dim3(256), 0, stream>>>(
        seq, Wih0, Whh0, bih0, bhh0, Wih1, Whh1, bih1, bhh1, linW, linb,
        A0p, A1p, outp, bar);
}

// Round 3
// 17678.314 us; speedup vs baseline: 1.1864x; 1.1048x over previous
//
#include <hip/hip_runtime.h>
#include <cstdint>
#include <cstddef>

#define LSEQ 512
#define NBLK 192
#define ASZ (128*256*8)   // halfs per h parity plane (512 KB)

typedef _Float16 f16;
typedef f16 f16x8 __attribute__((ext_vector_type(8)));
typedef float f32x4 __attribute__((ext_vector_type(4)));
typedef int v4i __attribute__((ext_vector_type(4)));
typedef unsigned long long u64t;

#define MFMA16(a, b, c) __builtin_amdgcn_mfma_f32_16x16x32_f16(a, b, c, 0, 0, 0)

static __device__ __forceinline__ float sigm(float x){ return 1.f/(1.f+__expf(-x)); }
static __device__ __forceinline__ float tanh_f(float x){
    x = fminf(fmaxf(x,-15.f),15.f);
    float t = __expf(-2.f*x);
    return (1.f-t)/(1.f+t);
}
static __device__ __forceinline__ f16x8 cvt8(const float* s){
    float4 a = *(const float4*)s, b = *(const float4*)(s+4);
    f16x8 v = {(f16)a.x,(f16)a.y,(f16)a.z,(f16)a.w,(f16)b.x,(f16)b.y,(f16)b.z,(f16)b.w};
    return v;
}

// ---- IC-coherent 16B load (R0-proven): SC0|SC1 bypasses L1+L2, served at
// the Infinity Cache (device coherence point). Compiler-managed waitcnts.
// R1's cached+per-step-inv variant REGRESSED (staggered buffer_inv thrash).
// R2's depth-4 prefetch was NEUTRAL (not per-thread-latency-bound).
static __device__ __forceinline__ uint4 ic_load(const char* base, int voff){
    __amdgpu_buffer_rsrc_t srd =
        __builtin_amdgcn_make_buffer_rsrc((void*)base, (short)0, -1, 0x00020000);
    v4i r = __builtin_amdgcn_raw_buffer_load_b128(srd, voff, 0, 0x11);
    return __builtin_bit_cast(uint4, r);
}
// 8B IC-coherent atomic ops (h stores + final read + barrier).
static __device__ __forceinline__ u64t hload(const u64t* p){
    return __hip_atomic_load(p, __ATOMIC_RELAXED, __HIP_MEMORY_SCOPE_AGENT);
}
static __device__ __forceinline__ void hstore(u64t* p, u64t v){
    __hip_atomic_store(p, v, __ATOMIC_RELAXED, __HIP_MEMORY_SCOPE_AGENT);
}
union U64F16 { u64t q; f16 h[4]; };
union U2F16x8 { u64t q[2]; f16x8 v; };

// Single chunk barrier (R3): iter = { ds_write buf[c&1]; lgkmcnt(0)+barrier;
// consume buf[c&1] }. A wave's chunk-(c-2) LDS reads are drained by its own
// lgkmcnt(0) before it reaches barrier c-1; the iter-c rewrite of that
// buffer happens only after barrier c-1 -> no hazard with ONE barrier/chunk.
// vmcnt deliberately NOT drained here (prefetch pipeline stays live).
#define SYNC_LGKM() do { __builtin_amdgcn_s_waitcnt(0xC07F); __builtin_amdgcn_s_barrier(); } while(0)

// Single-level grid barrier (R0-proven; R2's 2-level was neutral/worse).
static __device__ __forceinline__ void grid_barrier(int* bar){
    __builtin_amdgcn_s_waitcnt(0x0f70);   // vmcnt(0)
    __syncthreads();
    if (threadIdx.x == 0){
        int g = __hip_atomic_load(&bar[32], __ATOMIC_RELAXED, __HIP_MEMORY_SCOPE_AGENT);
        int old = __hip_atomic_fetch_add(&bar[0], 1, __ATOMIC_RELAXED, __HIP_MEMORY_SCOPE_AGENT);
        if (old == NBLK - 1){
            __hip_atomic_store(&bar[0], 0, __ATOMIC_RELAXED, __HIP_MEMORY_SCOPE_AGENT);
            __hip_atomic_store(&bar[32], g + 1, __ATOMIC_RELAXED, __HIP_MEMORY_SCOPE_AGENT);
        } else {
            while (__hip_atomic_load(&bar[32], __ATOMIC_RELAXED, __HIP_MEMORY_SCOPE_AGENT) == g)
                __builtin_amdgcn_s_sleep(2);
        }
    }
    __syncthreads();
}

// Blocks 0..127: L1 (mh=blk>>6 m-half 128 rows, nb=blk&63 -> 16 j-cols x 4 gates).
// Blocks 128..191: L0 (all 256 rows, nb -> 16 j-cols x 4 gates).
// Waves: nh=wav&1 (col-half, 32 gate-cols), kh=wav>>1 (K-half).
// R3: 16 chunks/step (2x size: L1 128 K, L0 64 K per chunk), ONE barrier per
// chunk -> 16 block-barriers/step vs 64. LDS dbuf 2x33 KB. IC traffic
// byte-identical to R0 (this round discriminates barrier-bound vs IC-BW-bound).
__global__ void __launch_bounds__(256, 1) lstm_persist(
    const float* __restrict__ seq,
    const float* __restrict__ Wih0, const float* __restrict__ Whh0,
    const float* __restrict__ bih0, const float* __restrict__ bhh0,
    const float* __restrict__ Wih1, const float* __restrict__ Whh1,
    const float* __restrict__ bih1, const float* __restrict__ bhh1,
    const float* __restrict__ linW, const float* __restrict__ linb,
    f16* __restrict__ A0, f16* __restrict__ A1, float* __restrict__ out,
    int* __restrict__ bar)
{
    __shared__ char  pool[66048] __attribute__((aligned(16)));
    __shared__ float ldsX[1536];
    __shared__ float ldsWx[384];
    __shared__ float ldsBias[64];
    float* poolf = (float*)pool;

    const int tid = threadIdx.x, lane = tid & 63, wav = tid >> 6;
    const int quad = lane >> 4, l15 = lane & 15;
    const int nh = wav & 1, kh = wav >> 1;
    const int blk = blockIdx.x;

    if (blk < 128){
        // ======================= L1 =======================
        const int mh = blk >> 6, nb = blk & 63;
        const int m0 = mh * 128, j0 = nb * 16;
        if (tid < 64){
            int R = (tid >> 4) * 1024 + j0 + (tid & 15);
            ldsBias[tid] = bih1[R] + bhh1[R];
        }
        // weights: w1[kg][nt], k = kh*1024 + kg*32 + quad*8 (kh=0 -> Wih1, kh=1 -> Whh1)
        f16x8 w1[32][2];
        {
            const float* Wsrc = kh ? Whh1 : Wih1;
            #pragma unroll
            for (int nt = 0; nt < 2; ++nt){
                int ct = nh * 32 + nt * 16 + l15;
                size_t Roff = (size_t)((ct >> 4) * 1024 + j0 + (ct & 15)) * 1024;
                #pragma unroll
                for (int kg = 0; kg < 32; ++kg)
                    w1[kg][nt] = cvt8(Wsrc + Roff + kg * 32 + quad * 8);
            }
        }
        float c1[8] = {0,0,0,0,0,0,0,0};

        for (int p = 0; p <= LSEQ; ++p){
            if (p >= 1){
                const char* P0 = (const char*)(A0 + (size_t)((p + 1) & 1) * ASZ); // h0[p-1]
                const char* P1 = (const char*)(A1 + (size_t)(p & 1) * ASZ);       // h1[p-2]
                u64t* W1p = (u64t*)(A1 + (size_t)((p + 1) & 1) * ASZ);            // h1[p-1]

                f32x4 acc[8][2];
                #pragma unroll
                for (int a = 0; a < 8; ++a){ acc[a][0] = (f32x4){0,0,0,0}; acc[a][1] = (f32x4){0,0,0,0}; }

                uint4 st[2][8];
                #pragma unroll
                for (int n = 0; n < 2; ++n)
                    #pragma unroll
                    for (int i = 0; i < 8; ++i){
                        int idx = i * 256 + tid, kc8l = idx >> 7, ml = idx & 127;
                        st[n][i] = ic_load(P0, ((n * 16 + kc8l) * 256 + m0 + ml) * 16);
                    }
                #pragma unroll
                for (int c = 0; c < 16; ++c){
                    {
                        char* dst = pool + (c & 1) * 33024;
                        #pragma unroll
                        for (int i = 0; i < 8; ++i){
                            int idx = i * 256 + tid, kc8l = idx >> 7, ml = idx & 127;
                            *(uint4*)(dst + kc8l * 2064 + ml * 16) = st[c & 1][i];
                        }
                    }
                    SYNC_LGKM();                              // one barrier per chunk
                    if (c < 14){
                        const int n = c + 2;
                        const char* P = (n < 8) ? P0 : P1;
                        const int kb = (n < 8) ? n * 16 : (n - 8) * 16;
                        #pragma unroll
                        for (int i = 0; i < 8; ++i){
                            int idx = i * 256 + tid, kc8l = idx >> 7, ml = idx & 127;
                            st[c & 1][i] = ic_load(P, ((kb + kc8l) * 256 + m0 + ml) * 16);
                        }
                    }
                    if (kh == ((c < 8) ? 0 : 1)){
                        const char* la = pool + (c & 1) * 33024;
                        const int cl = (c < 8) ? c : c - 8;
                        #pragma unroll
                        for (int kgl = 0; kgl < 4; ++kgl){
                            const int ckg = cl * 4 + kgl;
                            #pragma unroll
                            for (int mt = 0; mt < 8; ++mt){
                                f16x8 af = *(const f16x8*)(la + (kgl * 4 + quad) * 2064 + (mt * 16 + l15) * 16);
                                acc[mt][0] = MFMA16(af, w1[ckg][0], acc[mt][0]);
                                acc[mt][1] = MFMA16(af, w1[ckg][1], acc[mt][1]);
                            }
                        }
                    }
                }
                // ---- epilogue: K-reduce (kh1 -> kh0) via LDS, gather, pointwise ----
                __syncthreads();
                if (kh == 1){
                    #pragma unroll
                    for (int mt = 0; mt < 8; ++mt)
                        #pragma unroll
                        for (int nt = 0; nt < 2; ++nt){
                            int ct = nh * 32 + nt * 16 + l15;
                            *(f32x4*)(poolf + ct * 132 + mt * 16 + quad * 4) = acc[mt][nt];
                        }
                }
                __syncthreads();
                if (kh == 0){
                    #pragma unroll
                    for (int mt = 0; mt < 8; ++mt)
                        #pragma unroll
                        for (int nt = 0; nt < 2; ++nt){
                            int ct = nh * 32 + nt * 16 + l15;
                            f32x4 v = acc[mt][nt] + *(const f32x4*)(poolf + ct * 132 + mt * 16 + quad * 4);
                            *(f32x4*)(poolf + ct * 132 + mt * 16 + quad * 4) = v;
                        }
                }
                __syncthreads();
                {
                    const int m = tid >> 1, jh = tid & 1;
                    float hq[8];
                    #pragma unroll
                    for (int jj = 0; jj < 8; ++jj){
                        int j = jh * 8 + jj;
                        float gv[4];
                        #pragma unroll
                        for (int g = 0; g < 4; ++g)
                            gv[g] = poolf[(g * 16 + j) * 132 + m] + ldsBias[g * 16 + j];
                        float I = sigm(gv[0]), F = sigm(gv[1]), G = tanh_f(gv[2]), O = sigm(gv[3]);
                        float cn = F * c1[jj] + I * G;
                        c1[jj] = cn;
                        hq[jj] = O * tanh_f(cn);
                    }
                    const int kc8 = nb * 2 + jh;
                    #pragma unroll
                    for (int q = 0; q < 2; ++q){
                        U64F16 v;
                        #pragma unroll
                        for (int w = 0; w < 4; ++w) v.h[w] = (f16)hq[q * 4 + w];
                        hstore(W1p + (size_t)(kc8 * 256 + m0 + m) * 2 + q, v.q);
                    }
                }
            }
            grid_barrier(bar);
        }
    } else {
        // ======================= L0 =======================
        const int nb0 = blk - 128;
        const int j0 = nb0 * 16;
        if (tid < 64){
            int R = (tid >> 4) * 1024 + j0 + (tid & 15);
            ldsBias[tid] = bih0[R] + bhh0[R];
        }
        for (int t = tid; t < 384; t += 256){
            int ct = t / 6, i = t - ct * 6;
            int R = (ct >> 4) * 1024 + j0 + (ct & 15);
            ldsWx[t] = Wih0[(size_t)R * 6 + i];
        }
        f16x8 w0[16][2];
        {
            #pragma unroll
            for (int nt = 0; nt < 2; ++nt){
                int ct = nh * 32 + nt * 16 + l15;
                size_t Roff = (size_t)((ct >> 4) * 1024 + j0 + (ct & 15)) * 1024;
                #pragma unroll
                for (int kg = 0; kg < 16; ++kg)
                    w0[kg][nt] = cvt8(Whh0 + Roff + kh * 512 + kg * 32 + quad * 8);
            }
        }
        float c0[16];
        #pragma unroll
        for (int i = 0; i < 16; ++i) c0[i] = 0.f;

        for (int p = 0; p <= LSEQ; ++p){
            if (p < LSEQ){
                const char* P0 = (const char*)(A0 + (size_t)((p + 1) & 1) * ASZ); // h0[p-1]
                u64t* W0p = (u64t*)(A0 + (size_t)(p & 1) * ASZ);                  // h0[p]
                {   // stage x[p]
                    const float2* xp = (const float2*)(seq + (size_t)p * 1536);
                    float2* xd = (float2*)ldsX;
                    for (int i = tid; i < 768; i += 256) xd[i] = xp[i];
                }
                f32x4 acc[16][2];
                #pragma unroll
                for (int a = 0; a < 16; ++a){ acc[a][0] = (f32x4){0,0,0,0}; acc[a][1] = (f32x4){0,0,0,0}; }

                uint4 st[2][8];
                #pragma unroll
                for (int n = 0; n < 2; ++n)
                    #pragma unroll
                    for (int i = 0; i < 8; ++i){
                        int idx = i * 256 + tid, kc8l = idx >> 8, ml = idx & 255;
                        st[n][i] = ic_load(P0, ((n * 8 + kc8l) * 256 + ml) * 16);
                    }
                #pragma unroll
                for (int c = 0; c < 16; ++c){
                    {
                        char* dst = pool + (c & 1) * 32896;
                        #pragma unroll
                        for (int i = 0; i < 8; ++i){
                            int idx = i * 256 + tid, kc8l = idx >> 8, ml = idx & 255;
                            *(uint4*)(dst + kc8l * 4112 + ml * 16) = st[c & 1][i];
                        }
                    }
                    SYNC_LGKM();
                    if (c < 14){
                        const int kb = (c + 2) * 8;
                        #pragma unroll
                        for (int i = 0; i < 8; ++i){
                            int idx = i * 256 + tid, kc8l = idx >> 8, ml = idx & 255;
                            st[c & 1][i] = ic_load(P0, ((kb + kc8l) * 256 + ml) * 16);
                        }
                    }
                    if (kh == (c >> 3)){
                        const char* la = pool + (c & 1) * 32896;
                        #pragma unroll
                        for (int kgl = 0; kgl < 2; ++kgl){
                            const int ckg = (c & 7) * 2 + kgl;
                            #pragma unroll
                            for (int mt = 0; mt < 16; ++mt){
                                f16x8 af = *(const f16x8*)(la + (kgl * 4 + quad) * 4112 + (mt * 16 + l15) * 16);
                                acc[mt][0] = MFMA16(af, w0[ckg][0], acc[mt][0]);
                                acc[mt][1] = MFMA16(af, w0[ckg][1], acc[mt][1]);
                            }
                        }
                    }
                }
                // ---- epilogue: two m-half rounds ----
                #pragma unroll
                for (int hh = 0; hh < 2; ++hh){
                    __syncthreads();
                    if (kh == 1){
                        #pragma unroll
                        for (int mt = 8 * hh; mt < 8 * hh + 8; ++mt)
                            #pragma unroll
                            for (int nt = 0; nt < 2; ++nt){
                                int ct = nh * 32 + nt * 16 + l15;
                                *(f32x4*)(poolf + ct * 132 + (mt - 8 * hh) * 16 + quad * 4) = acc[mt][nt];
                            }
                    }
                    __syncthreads();
                    if (kh == 0){
                        #pragma unroll
                        for (int mt = 8 * hh; mt < 8 * hh + 8; ++mt)
                            #pragma unroll
                            for (int nt = 0; nt < 2; ++nt){
                                int ct = nh * 32 + nt * 16 + l15;
                                f32x4 v = acc[mt][nt] + *(const f32x4*)(poolf + ct * 132 + (mt - 8 * hh) * 16 + quad * 4);
                                *(f32x4*)(poolf + ct * 132 + (mt - 8 * hh) * 16 + quad * 4) = v;
                            }
                    }
                    __syncthreads();
                    {
                        const int ml = tid >> 1, jh = tid & 1;
                        const int ma = 128 * hh + ml;
                        float xv[6];
                        #pragma unroll
                        for (int i = 0; i < 6; ++i) xv[i] = ldsX[ma * 6 + i];
                        float hq[8];
                        #pragma unroll
                        for (int jj = 0; jj < 8; ++jj){
                            int j = jh * 8 + jj;
                            float gv[4];
                            #pragma unroll
                            for (int g = 0; g < 4; ++g){
                                float v = poolf[(g * 16 + j) * 132 + ml] + ldsBias[g * 16 + j];
                                #pragma unroll
                                for (int i = 0; i < 6; ++i) v += xv[i] * ldsWx[(g * 16 + j) * 6 + i];
                                gv[g] = v;
                            }
                            float I = sigm(gv[0]), F = sigm(gv[1]), G = tanh_f(gv[2]), O = sigm(gv[3]);
                            float cn = F * c0[hh * 8 + jj] + I * G;
                            c0[hh * 8 + jj] = cn;
                            hq[jj] = O * tanh_f(cn);
                        }
                        const int kc8 = nb0 * 2 + jh;
                        #pragma unroll
                        for (int q = 0; q < 2; ++q){
                            U64F16 v;
                            #pragma unroll
                            for (int w = 0; w < 4; ++w) v.h[w] = (f16)hq[q * 4 + w];
                            hstore(W0p + (size_t)(kc8 * 256 + ma) * 2 + q, v.q);
                        }
                    }
                }
            }
            grid_barrier(bar);
        }
        // ---- final linear on h1[511] (plane parity 1) ----
        {
            const u64t* hp = (const u64t*)(A1 + (size_t)ASZ);
            int n = nb0 * 4 + wav;
            float s = 0.f;
            #pragma unroll
            for (int u = 0; u < 2; ++u){
                int kc = u * 64 + lane;
                U2F16x8 t;
                t.q[0] = hload(hp + (size_t)(kc * 256 + n) * 2);
                t.q[1] = hload(hp + (size_t)(kc * 256 + n) * 2 + 1);
                #pragma unroll
                for (int j = 0; j < 8; ++j) s += (float)t.v[j] * linW[kc * 8 + j];
            }
            #pragma unroll
            for (int m = 32; m >= 1; m >>= 1) s += __shfl_xor(s, m, 64);
            if (lane == 0) out[n] = s + linb[0];
        }
    }
}

extern "C" void kernel_launch(void* const* d_in, const int* in_sizes, int n_in,
                              void* d_out, int out_size, void* d_ws, size_t ws_size,
                              hipStream_t stream)
{
    (void)in_sizes; (void)n_in; (void)out_size; (void)ws_size;
    const float* seq  = (const float*)d_in[0];
    const float* Wih0 = (const float*)d_in[1];
    const float* Whh0 = (const float*)d_in[2];
    const float* bih0 = (const float*)d_in[3];
    const float* bhh0 = (const float*)d_in[4];
    const float* Wih1 = (const float*)d_in[5];
    const float* Whh1 = (const float*)d_in[6];
    const float* bih1 = (const float*)d_in[7];
    const float* bhh1 = (const float*)d_in[8];
    const float* linW = (const float*)d_in[9];
    const float* linb = (const float*)d_in[10];
    float* outp = (float*)d_out;

    char* ws = (char*)d_ws;
    f16* A0p = (f16*)ws;                      // h0: [2][128 kc8][256 m][8] = 1 MB
    f16* A1p = (f16*)(ws + (1 << 20));        // h1: 1 MB
    int* bar = (int*)(ws + (2 << 20));        // barrier state

    (void)hipMemsetAsync(ws, 0, 2 << 20, stream);   // zero h parity planes
    (void)hipMemsetAsync(bar, 0, 256, stream);      // zero barrier

    lstm_persist<<<dim3(NBLK), dim3(256), 0, stream>>>(
        seq, Wih0, Whh0, bih0, bhh0, Wih1, Whh1, bih1, bhh1, linW, linb,
        A0p, A1p, outp, bar);
}